// Round 1
// baseline (322.366 us; speedup 1.0000x reference)
//
#include <hip/hip_runtime.h>
#include <hip/hip_bf16.h>

#define NEG_INF (-3.402823466e+38f)

// ---------------- wave reduction helpers ----------------
__device__ __forceinline__ float waveSum(float v) {
    for (int d = 32; d; d >>= 1) v += __shfl_xor(v, d, 64);
    return v;
}
__device__ __forceinline__ float waveMax(float v) {
    for (int d = 32; d; d >>= 1) v = fmaxf(v, __shfl_xor(v, d, 64));
    return v;
}

// ---------------- GEMM: C[M x 128] = A[M x 128] @ B[128 x 128] (+bias) ----------------
// block 256, tile 64 rows x 128 cols, micro-tile 4x8 per thread
__global__ __launch_bounds__(256) void gemm_kernel(
    const float* __restrict__ A, const float* __restrict__ B,
    const float* __restrict__ bias, float* __restrict__ C, int M)
{
    __shared__ float As[64][132];
    __shared__ float Bs[32][132];
    const int tid = threadIdx.x;
    const int tx = tid & 15;   // col group: cols tx*8 .. tx*8+7
    const int ty = tid >> 4;   // row group: rows ty*4 .. ty*4+3
    const int row0 = blockIdx.x * 64;

    // load A tile (64x128 floats = 2048 float4, 8 per thread)
    #pragma unroll
    for (int i = 0; i < 8; ++i) {
        int f = tid + i * 256;
        int r = f >> 5;
        int c = (f & 31) << 2;
        float4 v = make_float4(0.f, 0.f, 0.f, 0.f);
        if (row0 + r < M) v = *(const float4*)&A[(size_t)(row0 + r) * 128 + c];
        *(float4*)&As[r][c] = v;
    }

    float acc[4][8];
    #pragma unroll
    for (int i = 0; i < 4; ++i)
        #pragma unroll
        for (int j = 0; j < 8; ++j) acc[i][j] = 0.f;

    for (int kb = 0; kb < 4; ++kb) {
        __syncthreads();
        // load B rows kb*32..kb*32+31 (32x128 = 1024 float4, 4 per thread)
        #pragma unroll
        for (int i = 0; i < 4; ++i) {
            int f = tid + i * 256;
            int r = f >> 5;
            int c = (f & 31) << 2;
            *(float4*)&Bs[r][c] = *(const float4*)&B[(size_t)(kb * 32 + r) * 128 + c];
        }
        __syncthreads();
        #pragma unroll
        for (int k = 0; k < 32; ++k) {
            float bv[8];
            *(float4*)&bv[0] = *(const float4*)&Bs[k][tx * 8];
            *(float4*)&bv[4] = *(const float4*)&Bs[k][tx * 8 + 4];
            float av[4];
            #pragma unroll
            for (int i = 0; i < 4; ++i) av[i] = As[ty * 4 + i][kb * 32 + k];
            #pragma unroll
            for (int i = 0; i < 4; ++i)
                #pragma unroll
                for (int j = 0; j < 8; ++j) acc[i][j] += av[i] * bv[j];
        }
    }

    float bvec[8];
    #pragma unroll
    for (int j = 0; j < 8; ++j) bvec[j] = bias ? bias[tx * 8 + j] : 0.f;

    #pragma unroll
    for (int i = 0; i < 4; ++i) {
        int row = row0 + ty * 4 + i;
        if (row < M) {
            float4 o0 = make_float4(acc[i][0] + bvec[0], acc[i][1] + bvec[1],
                                    acc[i][2] + bvec[2], acc[i][3] + bvec[3]);
            float4 o1 = make_float4(acc[i][4] + bvec[4], acc[i][5] + bvec[5],
                                    acc[i][6] + bvec[6], acc[i][7] + bvec[7]);
            *(float4*)&C[(size_t)row * 128 + tx * 8]     = o0;
            *(float4*)&C[(size_t)row * 128 + tx * 8 + 4] = o1;
        }
    }
}

// ---------------- rel_logit[r] = rel_emb[r] @ (W_r @ a[2D:]) ----------------
__global__ void rel_logit_kernel(const float* __restrict__ W_r, const float* __restrict__ a,
                                 const float* __restrict__ rel_emb, float* __restrict__ rl,
                                 int n_rel, int rel_dim)
{
    __shared__ float a3[128];
    __shared__ float wa[128];
    int tid = threadIdx.x; // 128
    a3[tid] = a[256 + tid];
    __syncthreads();
    if (tid < rel_dim) {
        float s = 0.f;
        for (int d = 0; d < 128; ++d) s += W_r[tid * 128 + d] * a3[d];
        wa[tid] = s;
    }
    __syncthreads();
    if (tid < n_rel) {
        float s = 0.f;
        for (int k = 0; k < rel_dim; ++k) s += rel_emb[tid * rel_dim + k] * wa[k];
        rl[tid] = s;
    }
}

// ---------------- p[i] = h[i].a[0:128], q[i] = h[i].a[128:256]  (1 wave / node) ----------------
__global__ __launch_bounds__(256) void pq_kernel(const float* __restrict__ h, const float* __restrict__ a,
                                                 float* __restrict__ p, float* __restrict__ q, int N)
{
    int node = blockIdx.x * 4 + (threadIdx.x >> 6);
    int lane = threadIdx.x & 63;
    if (node >= N) return;
    float h0 = h[(size_t)node * 128 + lane];
    float h1 = h[(size_t)node * 128 + 64 + lane];
    float pp = h0 * a[lane] + h1 * a[64 + lane];
    float qq = h0 * a[128 + lane] + h1 * a[192 + lane];
    pp = waveSum(pp);
    qq = waveSum(qq);
    if (lane == 0) { p[node] = pp; q[node] = qq; }
}

// ---------------- CSR build: zero, histogram, scan, scatter ----------------
__global__ void zero_kernel(int* __restrict__ ptr, int n)
{
    int i = blockIdx.x * 256 + threadIdx.x;
    if (i < n) ptr[i] = 0;
}

__global__ void hist_kernel(const int* __restrict__ dst, int* __restrict__ counts, int E)
{
    int e = blockIdx.x * 256 + threadIdx.x;
    if (e < E) atomicAdd(&counts[dst[e]], 1);
}

// inclusive scan per 1024-block; incl -> tmp, block totals -> bsums
__global__ __launch_bounds__(1024) void scan_block(const int* __restrict__ counts, int* __restrict__ tmp,
                                                   int* __restrict__ bsums, int n)
{
    __shared__ int wsum[16];
    int tid = threadIdx.x;
    int i = blockIdx.x * 1024 + tid;
    int v = (i < n) ? counts[i] : 0;
    int lane = tid & 63, w = tid >> 6;
    int x = v;
    #pragma unroll
    for (int d = 1; d < 64; d <<= 1) { int t = __shfl_up(x, d, 64); if (lane >= d) x += t; }
    if (lane == 63) wsum[w] = x;
    __syncthreads();
    if (w == 0) {
        int s = (lane < 16) ? wsum[lane] : 0;
        #pragma unroll
        for (int d = 1; d < 16; d <<= 1) { int t = __shfl_up(s, d, 64); if (lane >= d) s += t; }
        if (lane < 16) wsum[lane] = s;
    }
    __syncthreads();
    if (w > 0) x += wsum[w - 1];
    if (i < n) tmp[i] = x;
    if (tid == 1023) bsums[blockIdx.x] = x;
}

__global__ void scan_partials(const int* __restrict__ bsums, int* __restrict__ bpref, int nb)
{
    int lane = threadIdx.x; // 64
    int v = (lane < nb) ? bsums[lane] : 0;
    int x = v;
    #pragma unroll
    for (int d = 1; d < 64; d <<= 1) { int t = __shfl_up(x, d, 64); if (lane >= d) x += t; }
    if (lane < nb) bpref[lane] = x - v; // exclusive
}

__global__ __launch_bounds__(1024) void finalize_offsets(const int* __restrict__ tmp, const int* __restrict__ counts,
                                                         const int* __restrict__ bpref, int* __restrict__ offsets,
                                                         int* __restrict__ cursor, int N, int E)
{
    int i = blockIdx.x * 1024 + threadIdx.x;
    if (i < N) {
        int ex = tmp[i] - counts[i] + bpref[blockIdx.x];
        offsets[i] = ex;
        cursor[i] = ex;
    }
    if (i == 0) offsets[N] = E;
}

// per-edge logit + CSR scatter
__global__ __launch_bounds__(256) void scatter_kernel(
    const int* __restrict__ src, const int* __restrict__ dst, const int* __restrict__ etype,
    const float* __restrict__ p, const float* __restrict__ q, const float* __restrict__ rl,
    int* __restrict__ cursor, int* __restrict__ ssrc, float* __restrict__ slog, int E, int n_rel)
{
    __shared__ float rls[64];
    if (threadIdx.x < n_rel) rls[threadIdx.x] = rl[threadIdx.x];
    __syncthreads();
    int e = blockIdx.x * 256 + threadIdx.x;
    if (e >= E) return;
    int s = src[e], d = dst[e], t = etype[e];
    float l = p[d] + q[s] + rls[t];
    l = (l > 0.f) ? l : 0.2f * l;
    int pos = atomicAdd(&cursor[d], 1);
    ssrc[pos] = s;
    slog[pos] = l;
}

// ---------------- per-node softmax + aggregate + residual + SELU (1 wave / node) ----------------
__global__ __launch_bounds__(256) void agg_kernel(
    const float* __restrict__ h, const float* __restrict__ res,
    const int* __restrict__ offsets, const int* __restrict__ ssrc, const float* __restrict__ slog,
    float* __restrict__ out, int N)
{
    int node = blockIdx.x * 4 + (threadIdx.x >> 6);
    int lane = threadIdx.x & 63;
    if (node >= N) return;
    int beg = offsets[node], end = offsets[node + 1];

    float m = NEG_INF;
    for (int e = beg + lane; e < end; e += 64) m = fmaxf(m, slog[e]);
    m = waveMax(m);
    float s = 0.f;
    for (int e = beg + lane; e < end; e += 64) s += __expf(slog[e] - m);
    s = waveSum(s);
    float inv = 1.0f / (s + 1e-16f);

    float a0 = 0.f, a1 = 0.f;
    for (int e = beg; e < end; ++e) {
        int sn = ssrc[e];
        float wgt = __expf(slog[e] - m) * inv;
        float2 hv = *(const float2*)(h + (size_t)sn * 128 + lane * 2);
        a0 += wgt * hv.x;
        a1 += wgt * hv.y;
    }

    float2 rv = *(const float2*)(res + (size_t)node * 128 + lane * 2);
    float o0 = a0 + rv.x, o1 = a1 + rv.y;
    const float SC = 1.0507009873554805f, AL = 1.6732632423543772f;
    o0 = (o0 > 0.f) ? SC * o0 : SC * AL * (__expf(o0) - 1.f);
    o1 = (o1 > 0.f) ? SC * o1 : SC * AL * (__expf(o1) - 1.f);
    *(float2*)(out + (size_t)node * 128 + lane * 2) = make_float2(o0, o1);
}

// ---------------- launch ----------------
extern "C" void kernel_launch(void* const* d_in, const int* in_sizes, int n_in,
                              void* d_out, int out_size, void* d_ws, size_t ws_size,
                              hipStream_t stream)
{
    const float* X      = (const float*)d_in[0];
    const int*   ei     = (const int*)d_in[1];
    const int*   etype  = (const int*)d_in[2];
    const float* W      = (const float*)d_in[3];
    const float* W_r    = (const float*)d_in[4];
    const float* a      = (const float*)d_in[5];
    const float* W_res  = (const float*)d_in[6];
    const float* b_res  = (const float*)d_in[7];
    const float* rel_emb= (const float*)d_in[8];

    const int N = in_sizes[0] / 128;   // 50000
    const int E = in_sizes[2];         // 600000
    const int n_rel = in_sizes[8] / 100; // 40
    const int* src = ei;
    const int* dst = ei + E;

    // workspace carve (256B aligned)
    char* w = (char*)d_ws;
    auto alloc = [&](size_t bytes) -> void* {
        void* ptr = (void*)w;
        w += (bytes + 255) & ~(size_t)255;
        return ptr;
    };
    float* h       = (float*)alloc((size_t)N * 128 * 4);
    float* res     = (float*)alloc((size_t)N * 128 * 4);
    float* p       = (float*)alloc((size_t)N * 4);
    float* q       = (float*)alloc((size_t)N * 4);
    float* rl      = (float*)alloc(64 * 4);
    int*   counts  = (int*)alloc((size_t)N * 4);
    int*   tmp     = (int*)alloc((size_t)(N + 2) * 4);
    int*   offsets = (int*)alloc((size_t)(N + 2) * 4);
    int*   cursor  = (int*)alloc((size_t)N * 4);
    int*   bsums   = (int*)alloc(256 * 4);
    int*   bpref   = (int*)alloc(256 * 4);
    int*   ssrc    = (int*)alloc((size_t)E * 4);
    float* slog    = (float*)alloc((size_t)E * 4);
    float* out     = (float*)d_out;

    const int gemm_blocks = (N + 63) / 64;          // 782
    const int node_wave_blocks = (N + 3) / 4;       // 12500
    const int edge_blocks = (E + 255) / 256;        // 2344
    const int scan_blocks = (N + 1023) / 1024;      // 49

    gemm_kernel<<<gemm_blocks, 256, 0, stream>>>(X, W, nullptr, h, N);
    gemm_kernel<<<gemm_blocks, 256, 0, stream>>>(X, W_res, b_res, res, N);
    rel_logit_kernel<<<1, 128, 0, stream>>>(W_r, a, rel_emb, rl, n_rel, 100);
    pq_kernel<<<node_wave_blocks, 256, 0, stream>>>(h, a, p, q, N);

    zero_kernel<<<(N + 255) / 256, 256, 0, stream>>>(counts, N);
    hist_kernel<<<edge_blocks, 256, 0, stream>>>(dst, counts, E);
    scan_block<<<scan_blocks, 1024, 0, stream>>>(counts, tmp, bsums, N);
    scan_partials<<<1, 64, 0, stream>>>(bsums, bpref, scan_blocks);
    finalize_offsets<<<scan_blocks, 1024, 0, stream>>>(tmp, counts, bpref, offsets, cursor, N, E);

    scatter_kernel<<<edge_blocks, 256, 0, stream>>>(src, dst, etype, p, q, rl,
                                                    cursor, ssrc, slog, E, n_rel);
    agg_kernel<<<node_wave_blocks, 256, 0, stream>>>(h, res, offsets, ssrc, slog, out, N);
}

// Round 2
// 247.855 us; speedup vs baseline: 1.3006x; 1.3006x over previous
//
#include <hip/hip_runtime.h>
#include <hip/hip_bf16.h>

typedef __attribute__((ext_vector_type(8))) short bf16x8;
typedef __attribute__((ext_vector_type(4))) float f32x4;

// ---------------- helpers ----------------
__device__ __forceinline__ float waveSum(float v) {
    for (int d = 32; d; d >>= 1) v += __shfl_xor(v, d, 64);
    return v;
}
__device__ __forceinline__ unsigned short f2bf(float f) {
    union { float f; unsigned int u; } v; v.f = f;
    unsigned int r = (v.u + 0x7FFF + ((v.u >> 16) & 1)) >> 16;
    return (unsigned short)r;
}
__device__ __forceinline__ float bf2f(unsigned int hbits) {
    union { unsigned int u; float f; } v; v.u = hbits << 16;
    return v.f;
}

// ---------------- prep: pack [W | W_res] into B-fragment order, bf16 ----------------
// WbPack[t][s][lane][j]  (t = 16-col tile 0..15, s = k-step 0..3, lane 0..63, j 0..7)
// frag element j corresponds to B[k0+j][n], k0 = s*32 + (lane>>4)*8, n = 16t + (lane&15)
__global__ __launch_bounds__(256) void prep_kernel(
    const float* __restrict__ W, const float* __restrict__ W_res,
    unsigned short* __restrict__ WbPack)
{
    int g = blockIdx.x * 256 + threadIdx.x;   // 0..4095
    if (g >= 16 * 4 * 64) return;
    int t = g >> 8;
    int s = (g >> 6) & 3;
    int lane = g & 63;
    int ncol = ((t & 7) << 4) + (lane & 15);
    int k0 = s * 32 + ((lane >> 4) << 3);
    const float* src = (t < 8) ? W : W_res;
    unsigned short* dst = WbPack + ((size_t)(t * 4 + s) * 64 + lane) * 8;
    #pragma unroll
    for (int j = 0; j < 8; ++j) dst[j] = f2bf(src[(size_t)(k0 + j) * 128 + ncol]);
}

// ---------------- rel_logit[r] = rel_emb[r] @ (W_r @ a[2D:]) ----------------
__global__ void rel_logit_kernel(const float* __restrict__ W_r, const float* __restrict__ a,
                                 const float* __restrict__ rel_emb, float* __restrict__ rl,
                                 int n_rel, int rel_dim)
{
    __shared__ float a3[128];
    __shared__ float wa[128];
    int tid = threadIdx.x; // 128
    a3[tid] = a[256 + tid];
    __syncthreads();
    if (tid < rel_dim) {
        float s = 0.f;
        for (int d = 0; d < 128; ++d) s += W_r[tid * 128 + d] * a3[d];
        wa[tid] = s;
    }
    __syncthreads();
    if (tid < n_rel) {
        float s = 0.f;
        for (int k = 0; k < rel_dim; ++k) s += rel_emb[tid * rel_dim + k] * wa[k];
        rl[tid] = s;
    }
}

// ---------------- dual GEMM via MFMA: [hb | resb] = bf16( X @ [W | W_res] ) ----------------
// 1 wave = 16 rows x 256 cols. K=128 in 4 steps of 32. 16 n-tiles of 16 cols.
__global__ __launch_bounds__(256) void gemm_dual_kernel(
    const float* __restrict__ X, const unsigned short* __restrict__ WbPack,
    const float* __restrict__ b_res,
    unsigned short* __restrict__ hb, unsigned short* __restrict__ resb, int M)
{
    const int lane = threadIdx.x & 63;
    const int wave = threadIdx.x >> 6;
    const int rowbase = (blockIdx.x * 4 + wave) * 16;
    if (rowbase >= M) return;

    f32x4 acc[16];
    #pragma unroll
    for (int t = 0; t < 16; ++t) acc[t] = (f32x4){0.f, 0.f, 0.f, 0.f};

    const int arow = rowbase + (lane & 15);
    const int kbase = (lane >> 4) << 3;   // 0,8,16,24

    #pragma unroll
    for (int s = 0; s < 4; ++s) {
        // A fragment: X[arow][s*32 + kbase .. +7], fp32 -> bf16
        const float* ap = X + (size_t)arow * 128 + s * 32 + kbase;
        float4 a0 = *(const float4*)ap;
        float4 a1 = *(const float4*)(ap + 4);
        union { bf16x8 v; unsigned short u[8]; } af;
        af.u[0] = f2bf(a0.x); af.u[1] = f2bf(a0.y); af.u[2] = f2bf(a0.z); af.u[3] = f2bf(a0.w);
        af.u[4] = f2bf(a1.x); af.u[5] = f2bf(a1.y); af.u[6] = f2bf(a1.z); af.u[7] = f2bf(a1.w);
        #pragma unroll
        for (int t = 0; t < 16; ++t) {
            bf16x8 bf = *(const bf16x8*)(WbPack + ((size_t)(t * 4 + s) * 64 + lane) * 8);
            acc[t] = __builtin_amdgcn_mfma_f32_16x16x32_bf16(af.v, bf, acc[t], 0, 0, 0);
        }
    }

    // Epilogue: C/D layout col=lane&15, row=(lane>>4)*4+reg
    const int col16 = lane & 15;
    const int rsub = (lane >> 4) << 2;
    #pragma unroll
    for (int t = 0; t < 16; ++t) {
        float badd = 0.f;
        int ncol = ((t & 7) << 4) + col16;
        if (t >= 8) badd = b_res[ncol];
        unsigned short* dstbase = (t < 8) ? hb : resb;
        #pragma unroll
        for (int i = 0; i < 4; ++i) {
            int row = rowbase + rsub + i;
            dstbase[(size_t)row * 128 + ncol] = f2bf(acc[t][i] + badd);
        }
    }
}

// ---------------- p[i] = h[i].a[0:128], q[i] = h[i].a[128:256]  (1 wave / node) ----------------
__global__ __launch_bounds__(256) void pq_kernel(const unsigned short* __restrict__ hb,
                                                 const float* __restrict__ a,
                                                 float* __restrict__ p, float* __restrict__ q, int N)
{
    int node = blockIdx.x * 4 + (threadIdx.x >> 6);
    int lane = threadIdx.x & 63;
    if (node >= N) return;
    unsigned int hv = *(const unsigned int*)(hb + (size_t)node * 128 + lane * 2);
    float h0 = bf2f(hv & 0xffff), h1 = bf2f(hv >> 16);
    float pp = h0 * a[lane * 2] + h1 * a[lane * 2 + 1];
    float qq = h0 * a[128 + lane * 2] + h1 * a[128 + lane * 2 + 1];
    pp = waveSum(pp);
    qq = waveSum(qq);
    if (lane == 0) { p[node] = pp; q[node] = qq; }
}

// ---------------- CSR build ----------------
__global__ void zero_kernel(int* __restrict__ ptr, int n)
{
    int i = blockIdx.x * 256 + threadIdx.x;
    if (i < n) ptr[i] = 0;
}

__global__ void hist_kernel(const int* __restrict__ dst, int* __restrict__ counts, int E)
{
    int e = blockIdx.x * 256 + threadIdx.x;
    if (e < E) atomicAdd(&counts[dst[e]], 1);
}

__global__ __launch_bounds__(1024) void scan_block(const int* __restrict__ counts, int* __restrict__ tmp,
                                                   int* __restrict__ bsums, int n)
{
    __shared__ int wsum[16];
    int tid = threadIdx.x;
    int i = blockIdx.x * 1024 + tid;
    int v = (i < n) ? counts[i] : 0;
    int lane = tid & 63, w = tid >> 6;
    int x = v;
    #pragma unroll
    for (int d = 1; d < 64; d <<= 1) { int t = __shfl_up(x, d, 64); if (lane >= d) x += t; }
    if (lane == 63) wsum[w] = x;
    __syncthreads();
    if (w == 0) {
        int s = (lane < 16) ? wsum[lane] : 0;
        #pragma unroll
        for (int d = 1; d < 16; d <<= 1) { int t = __shfl_up(s, d, 64); if (lane >= d) s += t; }
        if (lane < 16) wsum[lane] = s;
    }
    __syncthreads();
    if (w > 0) x += wsum[w - 1];
    if (i < n) tmp[i] = x;
    if (tid == 1023) bsums[blockIdx.x] = x;
}

__global__ void scan_partials(const int* __restrict__ bsums, int* __restrict__ bpref, int nb)
{
    int lane = threadIdx.x; // 64
    int v = (lane < nb) ? bsums[lane] : 0;
    int x = v;
    #pragma unroll
    for (int d = 1; d < 64; d <<= 1) { int t = __shfl_up(x, d, 64); if (lane >= d) x += t; }
    if (lane < nb) bpref[lane] = x - v; // exclusive
}

__global__ __launch_bounds__(1024) void finalize_offsets(const int* __restrict__ tmp, const int* __restrict__ counts,
                                                         const int* __restrict__ bpref, int* __restrict__ offsets,
                                                         int* __restrict__ cursor, int N, int E)
{
    int i = blockIdx.x * 1024 + threadIdx.x;
    if (i < N) {
        int ex = tmp[i] - counts[i] + bpref[blockIdx.x];
        offsets[i] = ex;
        cursor[i] = ex;
    }
    if (i == 0) offsets[N] = E;
}

// ---------------- per-edge logit -> exp, CSR scatter ----------------
// softmax is shift-invariant; logits are O(+-10) so exp() cannot overflow in fp32.
__global__ __launch_bounds__(256) void scatter_kernel(
    const int* __restrict__ src, const int* __restrict__ dst, const int* __restrict__ etype,
    const float* __restrict__ p, const float* __restrict__ q, const float* __restrict__ rl,
    int* __restrict__ cursor, int* __restrict__ ssrc, float* __restrict__ sexp, int E, int n_rel)
{
    __shared__ float rls[64];
    if (threadIdx.x < n_rel) rls[threadIdx.x] = rl[threadIdx.x];
    __syncthreads();
    int e = blockIdx.x * 256 + threadIdx.x;
    if (e >= E) return;
    int s = src[e], d = dst[e], t = etype[e];
    float l = p[d] + q[s] + rls[t];
    l = (l > 0.f) ? l : 0.2f * l;
    int pos = atomicAdd(&cursor[d], 1);
    ssrc[pos] = s;
    sexp[pos] = __expf(l);
}

// ---------------- per-node normalize + aggregate + residual + SELU (1 wave / node) ----------------
__global__ __launch_bounds__(256) void agg_kernel(
    const unsigned short* __restrict__ hb, const unsigned short* __restrict__ resb,
    const int* __restrict__ offsets, const int* __restrict__ ssrc, const float* __restrict__ sexp,
    float* __restrict__ out, int N)
{
    int node = blockIdx.x * 4 + (threadIdx.x >> 6);
    int lane = threadIdx.x & 63;
    if (node >= N) return;
    int beg = offsets[node], end = offsets[node + 1];

    // sum of exp
    float ssum = 0.f;
    for (int c = beg + lane; c < end; c += 64) ssum += sexp[c];
    ssum = waveSum(ssum);
    float inv = 1.0f / (ssum + 1e-16f);

    float a0 = 0.f, a1 = 0.f;
    const unsigned short* hlane = hb + lane * 2;
    for (int c = beg; c < end; c += 64) {
        int nn = min(64, end - c);
        float se = (lane < nn) ? sexp[c + lane] : 0.f;
        int   sv = (lane < nn) ? ssrc[c + lane] : 0;
        int j = 0;
        for (; j + 3 < nn; j += 4) {
            float w0 = __shfl(se, j) * inv, w1 = __shfl(se, j + 1) * inv;
            float w2 = __shfl(se, j + 2) * inv, w3 = __shfl(se, j + 3) * inv;
            int s0 = __shfl(sv, j), s1 = __shfl(sv, j + 1);
            int s2 = __shfl(sv, j + 2), s3 = __shfl(sv, j + 3);
            unsigned int v0 = *(const unsigned int*)(hlane + (size_t)s0 * 128);
            unsigned int v1 = *(const unsigned int*)(hlane + (size_t)s1 * 128);
            unsigned int v2 = *(const unsigned int*)(hlane + (size_t)s2 * 128);
            unsigned int v3 = *(const unsigned int*)(hlane + (size_t)s3 * 128);
            a0 += w0 * bf2f(v0 & 0xffff); a1 += w0 * bf2f(v0 >> 16);
            a0 += w1 * bf2f(v1 & 0xffff); a1 += w1 * bf2f(v1 >> 16);
            a0 += w2 * bf2f(v2 & 0xffff); a1 += w2 * bf2f(v2 >> 16);
            a0 += w3 * bf2f(v3 & 0xffff); a1 += w3 * bf2f(v3 >> 16);
        }
        for (; j < nn; ++j) {
            float w = __shfl(se, j) * inv;
            int s0 = __shfl(sv, j);
            unsigned int v0 = *(const unsigned int*)(hlane + (size_t)s0 * 128);
            a0 += w * bf2f(v0 & 0xffff); a1 += w * bf2f(v0 >> 16);
        }
    }

    unsigned int rv = *(const unsigned int*)(resb + (size_t)node * 128 + lane * 2);
    float o0 = a0 + bf2f(rv & 0xffff), o1 = a1 + bf2f(rv >> 16);
    const float SC = 1.0507009873554805f, AL = 1.6732632423543772f;
    o0 = (o0 > 0.f) ? SC * o0 : SC * AL * (__expf(o0) - 1.f);
    o1 = (o1 > 0.f) ? SC * o1 : SC * AL * (__expf(o1) - 1.f);
    *(float2*)(out + (size_t)node * 128 + lane * 2) = make_float2(o0, o1);
}

// ---------------- launch ----------------
extern "C" void kernel_launch(void* const* d_in, const int* in_sizes, int n_in,
                              void* d_out, int out_size, void* d_ws, size_t ws_size,
                              hipStream_t stream)
{
    const float* X      = (const float*)d_in[0];
    const int*   ei     = (const int*)d_in[1];
    const int*   etype  = (const int*)d_in[2];
    const float* W      = (const float*)d_in[3];
    const float* W_r    = (const float*)d_in[4];
    const float* a      = (const float*)d_in[5];
    const float* W_res  = (const float*)d_in[6];
    const float* b_res  = (const float*)d_in[7];
    const float* rel_emb= (const float*)d_in[8];

    const int N = in_sizes[0] / 128;     // 50000
    const int E = in_sizes[2];           // 600000
    const int n_rel = in_sizes[8] / 100; // 40
    const int* src = ei;
    const int* dst = ei + E;

    // workspace carve (256B aligned)
    char* w = (char*)d_ws;
    auto alloc = [&](size_t bytes) -> void* {
        void* ptr = (void*)w;
        w += (bytes + 255) & ~(size_t)255;
        return ptr;
    };
    unsigned short* WbPack = (unsigned short*)alloc((size_t)16 * 4 * 64 * 8 * 2);
    unsigned short* hb     = (unsigned short*)alloc((size_t)N * 128 * 2);
    unsigned short* resb   = (unsigned short*)alloc((size_t)N * 128 * 2);
    float* p       = (float*)alloc((size_t)N * 4);
    float* q       = (float*)alloc((size_t)N * 4);
    float* rl      = (float*)alloc(64 * 4);
    int*   counts  = (int*)alloc((size_t)N * 4);
    int*   tmp     = (int*)alloc((size_t)(N + 2) * 4);
    int*   offsets = (int*)alloc((size_t)(N + 2) * 4);
    int*   cursor  = (int*)alloc((size_t)N * 4);
    int*   bsums   = (int*)alloc(256 * 4);
    int*   bpref   = (int*)alloc(256 * 4);
    int*   ssrc    = (int*)alloc((size_t)E * 4);
    float* sexp    = (float*)alloc((size_t)E * 4);
    float* out     = (float*)d_out;

    const int gemm_blocks = (N / 16 + 3) / 4 + ((N % 16) ? 1 : 0); // waves of 16 rows, 4/block
    const int node_wave_blocks = (N + 3) / 4;       // 12500
    const int edge_blocks = (E + 255) / 256;        // 2344
    const int scan_blocks = (N + 1023) / 1024;      // 49

    prep_kernel<<<16, 256, 0, stream>>>(W, W_res, WbPack);
    rel_logit_kernel<<<1, 128, 0, stream>>>(W_r, a, rel_emb, rl, n_rel, 100);
    gemm_dual_kernel<<<gemm_blocks, 256, 0, stream>>>(X, WbPack, b_res, hb, resb, N);
    pq_kernel<<<node_wave_blocks, 256, 0, stream>>>(hb, a, p, q, N);

    zero_kernel<<<(N + 255) / 256, 256, 0, stream>>>(counts, N);
    hist_kernel<<<edge_blocks, 256, 0, stream>>>(dst, counts, E);
    scan_block<<<scan_blocks, 1024, 0, stream>>>(counts, tmp, bsums, N);
    scan_partials<<<1, 64, 0, stream>>>(bsums, bpref, scan_blocks);
    finalize_offsets<<<scan_blocks, 1024, 0, stream>>>(tmp, counts, bpref, offsets, cursor, N, E);

    scatter_kernel<<<edge_blocks, 256, 0, stream>>>(src, dst, etype, p, q, rl,
                                                    cursor, ssrc, sexp, E, n_rel);
    agg_kernel<<<node_wave_blocks, 256, 0, stream>>>(hb, resb, offsets, ssrc, sexp, out, N);
}

// Round 3
// 222.185 us; speedup vs baseline: 1.4509x; 1.1155x over previous
//
#include <hip/hip_runtime.h>
#include <hip/hip_bf16.h>

typedef __attribute__((ext_vector_type(8))) short bf16x8;
typedef __attribute__((ext_vector_type(4))) float f32x4;

// ---------------- helpers ----------------
__device__ __forceinline__ float waveSum(float v) {
    for (int d = 32; d; d >>= 1) v += __shfl_xor(v, d, 64);
    return v;
}
__device__ __forceinline__ unsigned short f2bf(float f) {
    union { float f; unsigned int u; } v; v.f = f;
    unsigned int r = (v.u + 0x7FFF + ((v.u >> 16) & 1)) >> 16;
    return (unsigned short)r;
}
__device__ __forceinline__ float bf2f(unsigned int hbits) {
    union { unsigned int u; float f; } v; v.u = hbits << 16;
    return v.f;
}

// ---------------- prep: pack [W | W_res] into B-fragment order, bf16 ----------------
__global__ __launch_bounds__(256) void prep_kernel(
    const float* __restrict__ W, const float* __restrict__ W_res,
    unsigned short* __restrict__ WbPack)
{
    int g = blockIdx.x * 256 + threadIdx.x;   // 0..4095
    if (g >= 16 * 4 * 64) return;
    int t = g >> 8;
    int s = (g >> 6) & 3;
    int lane = g & 63;
    int ncol = ((t & 7) << 4) + (lane & 15);
    int k0 = s * 32 + ((lane >> 4) << 3);
    const float* src = (t < 8) ? W : W_res;
    unsigned short* dst = WbPack + ((size_t)(t * 4 + s) * 64 + lane) * 8;
    #pragma unroll
    for (int j = 0; j < 8; ++j) dst[j] = f2bf(src[(size_t)(k0 + j) * 128 + ncol]);
}

// ---------------- rel_logit[r] = rel_emb[r] @ (W_r @ a[2D:]) ----------------
__global__ void rel_logit_kernel(const float* __restrict__ W_r, const float* __restrict__ a,
                                 const float* __restrict__ rel_emb, float* __restrict__ rl,
                                 int n_rel, int rel_dim)
{
    __shared__ float a3[128];
    __shared__ float wa[128];
    int tid = threadIdx.x; // 128
    a3[tid] = a[256 + tid];
    __syncthreads();
    if (tid < rel_dim) {
        float s = 0.f;
        for (int d = 0; d < 128; ++d) s += W_r[tid * 128 + d] * a3[d];
        wa[tid] = s;
    }
    __syncthreads();
    if (tid < n_rel) {
        float s = 0.f;
        for (int k = 0; k < rel_dim; ++k) s += rel_emb[tid * rel_dim + k] * wa[k];
        rl[tid] = s;
    }
}

// ---------------- dual GEMM via MFMA: [hb | resb] = bf16( X @ [W | W_res] ) ----------------
// also fuses p = h.a[0:128], q = h.a[128:256] from the fp32 accumulators.
__global__ __launch_bounds__(256) void gemm_dual_kernel(
    const float* __restrict__ X, const unsigned short* __restrict__ WbPack,
    const float* __restrict__ b_res, const float* __restrict__ a,
    unsigned short* __restrict__ hb, unsigned short* __restrict__ resb,
    float* __restrict__ p, float* __restrict__ q, int M)
{
    const int lane = threadIdx.x & 63;
    const int wave = threadIdx.x >> 6;
    const int rowbase = (blockIdx.x * 4 + wave) * 16;
    if (rowbase >= M) return;

    f32x4 acc[16];
    #pragma unroll
    for (int t = 0; t < 16; ++t) acc[t] = (f32x4){0.f, 0.f, 0.f, 0.f};

    int arow = rowbase + (lane & 15);
    if (arow >= M) arow = M - 1;
    const int kbase = (lane >> 4) << 3;   // 0,8,16,24

    #pragma unroll
    for (int s = 0; s < 4; ++s) {
        const float* ap = X + (size_t)arow * 128 + s * 32 + kbase;
        float4 a0 = *(const float4*)ap;
        float4 a1 = *(const float4*)(ap + 4);
        union { bf16x8 v; unsigned short u[8]; } af;
        af.u[0] = f2bf(a0.x); af.u[1] = f2bf(a0.y); af.u[2] = f2bf(a0.z); af.u[3] = f2bf(a0.w);
        af.u[4] = f2bf(a1.x); af.u[5] = f2bf(a1.y); af.u[6] = f2bf(a1.z); af.u[7] = f2bf(a1.w);
        #pragma unroll
        for (int t = 0; t < 16; ++t) {
            bf16x8 bf = *(const bf16x8*)(WbPack + ((size_t)(t * 4 + s) * 64 + lane) * 8);
            acc[t] = __builtin_amdgcn_mfma_f32_16x16x32_bf16(af.v, bf, acc[t], 0, 0, 0);
        }
    }

    // Epilogue: C/D layout col=lane&15, row=(lane>>4)*4+reg
    const int col16 = lane & 15;
    const int rsub = (lane >> 4) << 2;

    // p/q: lane holds h[row][t*16+col16] for t<8; reduce over 16-lane col groups
    float pa[8], qa[8];
    #pragma unroll
    for (int t = 0; t < 8; ++t) {
        pa[t] = a[t * 16 + col16];
        qa[t] = a[128 + t * 16 + col16];
    }
    #pragma unroll
    for (int i = 0; i < 4; ++i) {
        float pp = 0.f, qq = 0.f;
        #pragma unroll
        for (int t = 0; t < 8; ++t) { pp += acc[t][i] * pa[t]; qq += acc[t][i] * qa[t]; }
        #pragma unroll
        for (int d = 1; d < 16; d <<= 1) {
            pp += __shfl_xor(pp, d, 64);
            qq += __shfl_xor(qq, d, 64);
        }
        if (col16 == 0) {
            int row = rowbase + rsub + i;
            if (row < M) { p[row] = pp; q[row] = qq; }
        }
    }

    #pragma unroll
    for (int t = 0; t < 16; ++t) {
        float badd = 0.f;
        int ncol = ((t & 7) << 4) + col16;
        if (t >= 8) badd = b_res[ncol];
        unsigned short* dstbase = (t < 8) ? hb : resb;
        #pragma unroll
        for (int i = 0; i < 4; ++i) {
            int row = rowbase + rsub + i;
            if (row < M)
                dstbase[(size_t)row * 128 + ncol] = f2bf(acc[t][i] + badd);
        }
    }
}

// ---------------- CSR build ----------------
__global__ void zero_kernel(int* __restrict__ ptr, int n)
{
    int i = blockIdx.x * 256 + threadIdx.x;
    if (i < n) ptr[i] = 0;
}

// fused: logit -> exp (edge-order pack), histogram with rank capture
__global__ __launch_bounds__(256) void edge_kernel(
    const int* __restrict__ src, const int* __restrict__ dst, const int* __restrict__ etype,
    const float* __restrict__ p, const float* __restrict__ q, const float* __restrict__ rl,
    int* __restrict__ counts, int* __restrict__ rank, uint2* __restrict__ pair0,
    int E, int n_rel)
{
    __shared__ float rls[64];
    if (threadIdx.x < n_rel) rls[threadIdx.x] = rl[threadIdx.x];
    __syncthreads();
    int e = blockIdx.x * 256 + threadIdx.x;
    if (e >= E) return;
    int s = src[e], d = dst[e], t = etype[e];
    float l = p[d] + q[s] + rls[t];
    l = (l > 0.f) ? l : 0.2f * l;
    float ex = __expf(l);   // softmax shift-invariant; logits O(+-10), no overflow
    uint2 pk;
    pk.x = (unsigned int)s;
    pk.y = __float_as_uint(ex);
    pair0[e] = pk;                       // coalesced 8B
    rank[e] = atomicAdd(&counts[d], 1);  // rank within destination
}

__global__ __launch_bounds__(1024) void scan_block(const int* __restrict__ counts, int* __restrict__ tmp,
                                                   int* __restrict__ bsums, int n)
{
    __shared__ int wsum[16];
    int tid = threadIdx.x;
    int i = blockIdx.x * 1024 + tid;
    int v = (i < n) ? counts[i] : 0;
    int lane = tid & 63, w = tid >> 6;
    int x = v;
    #pragma unroll
    for (int d = 1; d < 64; d <<= 1) { int t = __shfl_up(x, d, 64); if (lane >= d) x += t; }
    if (lane == 63) wsum[w] = x;
    __syncthreads();
    if (w == 0) {
        int s = (lane < 16) ? wsum[lane] : 0;
        #pragma unroll
        for (int d = 1; d < 16; d <<= 1) { int t = __shfl_up(s, d, 64); if (lane >= d) s += t; }
        if (lane < 16) wsum[lane] = s;
    }
    __syncthreads();
    if (w > 0) x += wsum[w - 1];
    if (i < n) tmp[i] = x;
    if (tid == 1023) bsums[blockIdx.x] = x;
}

__global__ void scan_partials(const int* __restrict__ bsums, int* __restrict__ bpref, int nb)
{
    int lane = threadIdx.x; // 64
    int v = (lane < nb) ? bsums[lane] : 0;
    int x = v;
    #pragma unroll
    for (int d = 1; d < 64; d <<= 1) { int t = __shfl_up(x, d, 64); if (lane >= d) x += t; }
    if (lane < nb) bpref[lane] = x - v; // exclusive
}

__global__ __launch_bounds__(1024) void finalize_offsets(const int* __restrict__ tmp, const int* __restrict__ counts,
                                                         const int* __restrict__ bpref, int* __restrict__ offsets,
                                                         int N, int E)
{
    int i = blockIdx.x * 1024 + threadIdx.x;
    if (i < N) offsets[i] = tmp[i] - counts[i] + bpref[blockIdx.x];
    if (i == 0) offsets[N] = E;
}

// ---------------- permute: pairs[offsets[d] + rank[e]] = pair0[e] ----------------
// no atomics; one 8B scattered store per edge.
__global__ __launch_bounds__(256) void scatter_kernel(
    const int* __restrict__ dst, const int* __restrict__ rank,
    const int* __restrict__ offsets, const uint2* __restrict__ pair0,
    uint2* __restrict__ pairs, int E)
{
    int e = blockIdx.x * 256 + threadIdx.x;
    if (e >= E) return;
    int d = dst[e];
    int pos = offsets[d] + rank[e];
    pairs[pos] = pair0[e];
}

// ---------------- per-node normalize + aggregate + residual + SELU (1 wave / node) ----------------
__global__ __launch_bounds__(256) void agg_kernel(
    const unsigned short* __restrict__ hb, const unsigned short* __restrict__ resb,
    const int* __restrict__ offsets, const uint2* __restrict__ pairs,
    float* __restrict__ out, int N)
{
    int node = blockIdx.x * 4 + (threadIdx.x >> 6);
    int lane = threadIdx.x & 63;
    if (node >= N) return;
    int beg = offsets[node], end = offsets[node + 1];

    float a0 = 0.f, a1 = 0.f;
    float ssum = 0.f;
    const unsigned short* hlane = hb + lane * 2;
    for (int c = beg; c < end; c += 64) {
        int nn = min(64, end - c);
        uint2 pk = (lane < nn) ? pairs[c + lane] : make_uint2(0u, 0u);
        int   sv = (int)pk.x;
        float se = __uint_as_float(pk.y);
        if (lane < nn) ssum += se;
        int j = 0;
        for (; j + 3 < nn; j += 4) {
            float w0 = __shfl(se, j), w1 = __shfl(se, j + 1);
            float w2 = __shfl(se, j + 2), w3 = __shfl(se, j + 3);
            int s0 = __shfl(sv, j), s1 = __shfl(sv, j + 1);
            int s2 = __shfl(sv, j + 2), s3 = __shfl(sv, j + 3);
            unsigned int v0 = *(const unsigned int*)(hlane + (size_t)s0 * 128);
            unsigned int v1 = *(const unsigned int*)(hlane + (size_t)s1 * 128);
            unsigned int v2 = *(const unsigned int*)(hlane + (size_t)s2 * 128);
            unsigned int v3 = *(const unsigned int*)(hlane + (size_t)s3 * 128);
            a0 += w0 * bf2f(v0 & 0xffff); a1 += w0 * bf2f(v0 >> 16);
            a0 += w1 * bf2f(v1 & 0xffff); a1 += w1 * bf2f(v1 >> 16);
            a0 += w2 * bf2f(v2 & 0xffff); a1 += w2 * bf2f(v2 >> 16);
            a0 += w3 * bf2f(v3 & 0xffff); a1 += w3 * bf2f(v3 >> 16);
        }
        for (; j < nn; ++j) {
            float w = __shfl(se, j);
            int s0 = __shfl(sv, j);
            unsigned int v0 = *(const unsigned int*)(hlane + (size_t)s0 * 128);
            a0 += w * bf2f(v0 & 0xffff); a1 += w * bf2f(v0 >> 16);
        }
    }
    ssum = waveSum(ssum);
    float inv = 1.0f / (ssum + 1e-16f);
    a0 *= inv; a1 *= inv;

    unsigned int rv = *(const unsigned int*)(resb + (size_t)node * 128 + lane * 2);
    float o0 = a0 + bf2f(rv & 0xffff), o1 = a1 + bf2f(rv >> 16);
    const float SC = 1.0507009873554805f, AL = 1.6732632423543772f;
    o0 = (o0 > 0.f) ? SC * o0 : SC * AL * (__expf(o0) - 1.f);
    o1 = (o1 > 0.f) ? SC * o1 : SC * AL * (__expf(o1) - 1.f);
    *(float2*)(out + (size_t)node * 128 + lane * 2) = make_float2(o0, o1);
}

// ---------------- launch ----------------
extern "C" void kernel_launch(void* const* d_in, const int* in_sizes, int n_in,
                              void* d_out, int out_size, void* d_ws, size_t ws_size,
                              hipStream_t stream)
{
    const float* X      = (const float*)d_in[0];
    const int*   ei     = (const int*)d_in[1];
    const int*   etype  = (const int*)d_in[2];
    const float* W      = (const float*)d_in[3];
    const float* W_r    = (const float*)d_in[4];
    const float* a      = (const float*)d_in[5];
    const float* W_res  = (const float*)d_in[6];
    const float* b_res  = (const float*)d_in[7];
    const float* rel_emb= (const float*)d_in[8];

    const int N = in_sizes[0] / 128;     // 50000
    const int E = in_sizes[2];           // 600000
    const int n_rel = in_sizes[8] / 100; // 40
    const int* src = ei;
    const int* dst = ei + E;

    // workspace carve (256B aligned)
    char* w = (char*)d_ws;
    auto alloc = [&](size_t bytes) -> void* {
        void* ptr = (void*)w;
        w += (bytes + 255) & ~(size_t)255;
        return ptr;
    };
    unsigned short* WbPack = (unsigned short*)alloc((size_t)16 * 4 * 64 * 8 * 2);
    unsigned short* hb     = (unsigned short*)alloc((size_t)N * 128 * 2);
    unsigned short* resb   = (unsigned short*)alloc((size_t)N * 128 * 2);
    float* p       = (float*)alloc((size_t)N * 4);
    float* q       = (float*)alloc((size_t)N * 4);
    float* rl      = (float*)alloc(64 * 4);
    int*   counts  = (int*)alloc((size_t)N * 4);
    int*   tmp     = (int*)alloc((size_t)(N + 2) * 4);
    int*   offsets = (int*)alloc((size_t)(N + 2) * 4);
    int*   bsums   = (int*)alloc(256 * 4);
    int*   bpref   = (int*)alloc(256 * 4);
    int*   rank    = (int*)alloc((size_t)E * 4);
    uint2* pair0   = (uint2*)alloc((size_t)E * 8);
    uint2* pairs   = (uint2*)alloc((size_t)E * 8);
    float* out     = (float*)d_out;

    const int gemm_blocks = ((N + 15) / 16 + 3) / 4;
    const int node_wave_blocks = (N + 3) / 4;       // 12500
    const int edge_blocks = (E + 255) / 256;        // 2344
    const int scan_blocks = (N + 1023) / 1024;      // 49

    prep_kernel<<<16, 256, 0, stream>>>(W, W_res, WbPack);
    rel_logit_kernel<<<1, 128, 0, stream>>>(W_r, a, rel_emb, rl, n_rel, 100);
    zero_kernel<<<(N + 255) / 256, 256, 0, stream>>>(counts, N);
    gemm_dual_kernel<<<gemm_blocks, 256, 0, stream>>>(X, WbPack, b_res, a, hb, resb, p, q, N);

    edge_kernel<<<edge_blocks, 256, 0, stream>>>(src, dst, etype, p, q, rl,
                                                 counts, rank, pair0, E, n_rel);
    scan_block<<<scan_blocks, 1024, 0, stream>>>(counts, tmp, bsums, N);
    scan_partials<<<1, 64, 0, stream>>>(bsums, bpref, scan_blocks);
    finalize_offsets<<<scan_blocks, 1024, 0, stream>>>(tmp, counts, bpref, offsets, N, E);

    scatter_kernel<<<edge_blocks, 256, 0, stream>>>(dst, rank, offsets, pair0, pairs, E);
    agg_kernel<<<node_wave_blocks, 256, 0, stream>>>(hb, resb, offsets, pairs, out, N);
}

// Round 4
// 191.540 us; speedup vs baseline: 1.6830x; 1.1600x over previous
//
#include <hip/hip_runtime.h>
#include <hip/hip_bf16.h>

typedef __attribute__((ext_vector_type(8))) short bf16x8;
typedef __attribute__((ext_vector_type(4))) float f32x4;

#define LDS_STRIDE 528   // bytes per LDS row (132 dwords; %32 banks = 4, 16B-aligned)

// ---------------- helpers ----------------
__device__ __forceinline__ float waveSum(float v) {
    for (int d = 32; d; d >>= 1) v += __shfl_xor(v, d, 64);
    return v;
}
__device__ __forceinline__ unsigned short f2bf(float f) {
    union { float f; unsigned int u; } v; v.f = f;
    unsigned int r = (v.u + 0x7FFF + ((v.u >> 16) & 1)) >> 16;
    return (unsigned short)r;
}
__device__ __forceinline__ float bf2f(unsigned int hbits) {
    union { unsigned int u; float f; } v; v.u = hbits << 16;
    return v.f;
}

// ---------------- setup: zero counts | pack [W|W_res] to B-frag order | rel_logit ----------------
// blocks [0,zb): zero counts; [zb, zb+16): prep WbPack; zb+16: rel_logit
__global__ __launch_bounds__(256) void setup_kernel(
    int* __restrict__ counts, int N,
    const float* __restrict__ W, const float* __restrict__ W_res,
    unsigned short* __restrict__ WbPack,
    const float* __restrict__ W_r, const float* __restrict__ a,
    const float* __restrict__ rel_emb, float* __restrict__ rl,
    int n_rel, int rel_dim, int zb)
{
    __shared__ float a3[128];
    __shared__ float wa[128];
    int bid = blockIdx.x;
    int tid = threadIdx.x;
    if (bid < zb) {
        int i = bid * 256 + tid;
        if (i < N) counts[i] = 0;
        return;
    }
    if (bid < zb + 16) {
        int g = (bid - zb) * 256 + tid;   // 0..4095
        int t = g >> 8;
        int s = (g >> 6) & 3;
        int lane = g & 63;
        int ncol = ((t & 7) << 4) + (lane & 15);
        int k0 = s * 32 + ((lane >> 4) << 3);
        const float* srcw = (t < 8) ? W : W_res;
        unsigned short* dst = WbPack + ((size_t)(t * 4 + s) * 64 + lane) * 8;
        #pragma unroll
        for (int j = 0; j < 8; ++j) dst[j] = f2bf(srcw[(size_t)(k0 + j) * 128 + ncol]);
        return;
    }
    // rel_logit block
    if (tid < 128) {
        a3[tid] = a[256 + tid];
    }
    __syncthreads();
    if (tid < rel_dim) {
        float s = 0.f;
        for (int d = 0; d < 128; ++d) s += W_r[tid * 128 + d] * a3[d];
        wa[tid] = s;
    }
    __syncthreads();
    if (tid < n_rel) {
        float s = 0.f;
        for (int k = 0; k < rel_dim; ++k) s += rel_emb[tid * rel_dim + k] * wa[k];
        rl[tid] = s;
    }
}

// ---------------- dual GEMM via MFMA: [hb | resb] = bf16( X @ [W | W_res] ) + fused p/q ----------------
// block = 256 threads (4 waves), 64 rows. Col-split: wave w owns col-tiles t = 4w..4w+3.
// W fragments hoisted to registers once; X staged to LDS as bf16; epilogue LDS-transposed.
__global__ __launch_bounds__(256) void gemm_dual_kernel(
    const float* __restrict__ X, const unsigned short* __restrict__ WbPack,
    const float* __restrict__ b_res, const float* __restrict__ a,
    unsigned short* __restrict__ hb, unsigned short* __restrict__ resb,
    float* __restrict__ p, float* __restrict__ q, int M)
{
    __shared__ __align__(16) unsigned char smem[64 * LDS_STRIDE];
    __shared__ float pq_s[128];
    const int tid = threadIdx.x;
    const int lane = tid & 63;
    const int wave = tid >> 6;
    const int rowbase = blockIdx.x * 64;
    const int c16 = lane & 15;
    const int kq = lane >> 4;    // 0..3

    if (tid < 128) pq_s[tid] = 0.f;

    // hoist this wave's 16 W fragments (t = wave*4+tt, s = 0..3)
    bf16x8 wfrag[4][4];
    #pragma unroll
    for (int tt = 0; tt < 4; ++tt)
        #pragma unroll
        for (int s = 0; s < 4; ++s)
            wfrag[tt][s] = *(const bf16x8*)(WbPack + ((size_t)((wave * 4 + tt) * 4 + s) * 64 + lane) * 8);

    // b_res values for this wave's cols (only used when t>=8)
    float bres[4];
    #pragma unroll
    for (int tt = 0; tt < 4; ++tt) {
        int t = wave * 4 + tt;
        bres[tt] = (t >= 8) ? b_res[(t - 8) * 16 + c16] : 0.f;
    }
    // a-vector values for p/q (only waves 0,1 hold h cols)
    float pa[4], qa[4];
    #pragma unroll
    for (int tt = 0; tt < 4; ++tt) {
        int col = (wave * 4 + tt) * 16 + c16;
        pa[tt] = (wave < 2) ? a[col] : 0.f;
        qa[tt] = (wave < 2) ? a[128 + col] : 0.f;
    }

    // stage X tile (64 rows x 128 f32) -> LDS bf16, coalesced 4KB per inst
    #pragma unroll
    for (int j = 0; j < 8; ++j) {
        int ch = j * 256 + tid;            // 16B chunk id, 0..2047
        int r = ch >> 5;                   // row 0..63
        int c = ch & 31;                   // chunk in row
        int gr = rowbase + r; if (gr >= M) gr = M - 1;
        float4 v = *(const float4*)(X + (size_t)gr * 128 + c * 4);
        unsigned int u0 = ((unsigned)f2bf(v.y) << 16) | f2bf(v.x);
        unsigned int u1 = ((unsigned)f2bf(v.w) << 16) | f2bf(v.z);
        *(uint2*)(smem + r * LDS_STRIDE + c * 8) = make_uint2(u0, u1);
    }
    __syncthreads();

    f32x4 acc[4][4];   // [row-tile][col-tile]
    #pragma unroll
    for (int rt = 0; rt < 4; ++rt)
        #pragma unroll
        for (int tt = 0; tt < 4; ++tt) acc[rt][tt] = (f32x4){0.f, 0.f, 0.f, 0.f};

    #pragma unroll
    for (int s = 0; s < 4; ++s) {
        #pragma unroll
        for (int rt = 0; rt < 4; ++rt) {
            int row = rt * 16 + c16;
            bf16x8 af = *(const bf16x8*)(smem + row * LDS_STRIDE + s * 64 + kq * 16);
            #pragma unroll
            for (int tt = 0; tt < 4; ++tt)
                acc[rt][tt] = __builtin_amdgcn_mfma_f32_16x16x32_bf16(af, wfrag[tt][s], acc[rt][tt], 0, 0, 0);
        }
    }
    __syncthreads();   // LDS about to be reused for transpose

    // p/q partials (waves 0,1 only): reduce over 16-lane col groups, accumulate in LDS
    if (wave < 2) {
        #pragma unroll
        for (int rt = 0; rt < 4; ++rt) {
            #pragma unroll
            for (int i = 0; i < 4; ++i) {
                float pp = 0.f, qq = 0.f;
                #pragma unroll
                for (int tt = 0; tt < 4; ++tt) {
                    pp += acc[rt][tt][i] * pa[tt];
                    qq += acc[rt][tt][i] * qa[tt];
                }
                #pragma unroll
                for (int d = 1; d < 16; d <<= 1) {
                    pp += __shfl_xor(pp, d, 64);
                    qq += __shfl_xor(qq, d, 64);
                }
                if (c16 == 0) {
                    int r = rt * 16 + kq * 4 + i;
                    atomicAdd(&pq_s[r], pp);
                    atomicAdd(&pq_s[64 + r], qq);
                }
            }
        }
    }

    // transpose: accs -> LDS bf16, row-major [64][256]
    #pragma unroll
    for (int rt = 0; rt < 4; ++rt) {
        #pragma unroll
        for (int tt = 0; tt < 4; ++tt) {
            int colall = (wave * 4 + tt) * 16 + c16;   // 0..255
            #pragma unroll
            for (int i = 0; i < 4; ++i) {
                int row = rt * 16 + kq * 4 + i;
                *(unsigned short*)(smem + row * LDS_STRIDE + colall * 2) = f2bf(acc[rt][tt][i] + bres[tt]);
            }
        }
    }
    __syncthreads();

    // coalesced write-back: hb = cols 0..127, resb = cols 128..255
    #pragma unroll
    for (int j = 0; j < 4; ++j) {
        int ch = j * 256 + tid;        // 0..1023
        int r = ch >> 4;               // row 0..63
        int c = ch & 15;               // 16B chunk
        int gr = rowbase + r;
        uint4 hv = *(const uint4*)(smem + r * LDS_STRIDE + c * 16);
        uint4 rv = *(const uint4*)(smem + r * LDS_STRIDE + 256 + c * 16);
        if (gr < M) {
            *(uint4*)(hb + (size_t)gr * 128 + c * 8) = hv;
            *(uint4*)(resb + (size_t)gr * 128 + c * 8) = rv;
        }
    }
    if (tid < 64) {
        int gr = rowbase + tid;
        if (gr < M) { p[gr] = pq_s[tid]; q[gr] = pq_s[64 + tid]; }
    }
}

// ---------------- fused: logit -> exp (edge-order pack), histogram with rank capture ----------------
__global__ __launch_bounds__(256) void edge_kernel(
    const int* __restrict__ src, const int* __restrict__ dst, const int* __restrict__ etype,
    const float* __restrict__ p, const float* __restrict__ q, const float* __restrict__ rl,
    int* __restrict__ counts, int* __restrict__ rank, uint2* __restrict__ pair0,
    int E, int n_rel)
{
    __shared__ float rls[64];
    if (threadIdx.x < n_rel) rls[threadIdx.x] = rl[threadIdx.x];
    __syncthreads();
    int e = blockIdx.x * 256 + threadIdx.x;
    if (e >= E) return;
    int s = src[e], d = dst[e], t = etype[e];
    float l = p[d] + q[s] + rls[t];
    l = (l > 0.f) ? l : 0.2f * l;
    float ex = __expf(l);   // softmax shift-invariant; logits O(+-10), no overflow
    uint2 pk;
    pk.x = (unsigned int)s;
    pk.y = __float_as_uint(ex);
    pair0[e] = pk;
    rank[e] = atomicAdd(&counts[d], 1);
}

__global__ __launch_bounds__(1024) void scan_block(const int* __restrict__ counts, int* __restrict__ tmp,
                                                   int* __restrict__ bsums, int n)
{
    __shared__ int wsum[16];
    int tid = threadIdx.x;
    int i = blockIdx.x * 1024 + tid;
    int v = (i < n) ? counts[i] : 0;
    int lane = tid & 63, w = tid >> 6;
    int x = v;
    #pragma unroll
    for (int d = 1; d < 64; d <<= 1) { int t = __shfl_up(x, d, 64); if (lane >= d) x += t; }
    if (lane == 63) wsum[w] = x;
    __syncthreads();
    if (w == 0) {
        int s = (lane < 16) ? wsum[lane] : 0;
        #pragma unroll
        for (int d = 1; d < 16; d <<= 1) { int t = __shfl_up(s, d, 64); if (lane >= d) s += t; }
        if (lane < 16) wsum[lane] = s;
    }
    __syncthreads();
    if (w > 0) x += wsum[w - 1];
    if (i < n) tmp[i] = x;
    if (tid == 1023) bsums[blockIdx.x] = x;
}

__global__ void scan_partials(const int* __restrict__ bsums, int* __restrict__ bpref, int nb)
{
    int lane = threadIdx.x; // 64
    int v = (lane < nb) ? bsums[lane] : 0;
    int x = v;
    #pragma unroll
    for (int d = 1; d < 64; d <<= 1) { int t = __shfl_up(x, d, 64); if (lane >= d) x += t; }
    if (lane < nb) bpref[lane] = x - v; // exclusive
}

__global__ __launch_bounds__(1024) void finalize_offsets(const int* __restrict__ tmp, const int* __restrict__ counts,
                                                         const int* __restrict__ bpref, int* __restrict__ offsets,
                                                         int N, int E)
{
    int i = blockIdx.x * 1024 + threadIdx.x;
    if (i < N) offsets[i] = tmp[i] - counts[i] + bpref[blockIdx.x];
    if (i == 0) offsets[N] = E;
}

// ---------------- permute: pairs[offsets[d] + rank[e]] = pair0[e] ----------------
__global__ __launch_bounds__(256) void scatter_kernel(
    const int* __restrict__ dst, const int* __restrict__ rank,
    const int* __restrict__ offsets, const uint2* __restrict__ pair0,
    uint2* __restrict__ pairs, int E)
{
    int e = blockIdx.x * 256 + threadIdx.x;
    if (e >= E) return;
    int d = dst[e];
    int pos = offsets[d] + rank[e];
    pairs[pos] = pair0[e];
}

// ---------------- per-node normalize + aggregate + residual + SELU (1 wave / node) ----------------
__global__ __launch_bounds__(256) void agg_kernel(
    const unsigned short* __restrict__ hb, const unsigned short* __restrict__ resb,
    const int* __restrict__ offsets, const uint2* __restrict__ pairs,
    float* __restrict__ out, int N)
{
    int node = blockIdx.x * 4 + (threadIdx.x >> 6);
    int lane = threadIdx.x & 63;
    if (node >= N) return;
    int beg = offsets[node], end = offsets[node + 1];

    float a0 = 0.f, a1 = 0.f;
    float ssum = 0.f;
    const unsigned short* hlane = hb + lane * 2;
    for (int c = beg; c < end; c += 64) {
        int nn = min(64, end - c);
        uint2 pk = (lane < nn) ? pairs[c + lane] : make_uint2(0u, 0u);
        int   sv = (int)pk.x;
        float se = __uint_as_float(pk.y);
        if (lane < nn) ssum += se;
        int j = 0;
        for (; j + 3 < nn; j += 4) {
            float w0 = __shfl(se, j), w1 = __shfl(se, j + 1);
            float w2 = __shfl(se, j + 2), w3 = __shfl(se, j + 3);
            int s0 = __shfl(sv, j), s1 = __shfl(sv, j + 1);
            int s2 = __shfl(sv, j + 2), s3 = __shfl(sv, j + 3);
            unsigned int v0 = *(const unsigned int*)(hlane + (size_t)s0 * 128);
            unsigned int v1 = *(const unsigned int*)(hlane + (size_t)s1 * 128);
            unsigned int v2 = *(const unsigned int*)(hlane + (size_t)s2 * 128);
            unsigned int v3 = *(const unsigned int*)(hlane + (size_t)s3 * 128);
            a0 += w0 * bf2f(v0 & 0xffff); a1 += w0 * bf2f(v0 >> 16);
            a0 += w1 * bf2f(v1 & 0xffff); a1 += w1 * bf2f(v1 >> 16);
            a0 += w2 * bf2f(v2 & 0xffff); a1 += w2 * bf2f(v2 >> 16);
            a0 += w3 * bf2f(v3 & 0xffff); a1 += w3 * bf2f(v3 >> 16);
        }
        for (; j < nn; ++j) {
            float w = __shfl(se, j);
            int s0 = __shfl(sv, j);
            unsigned int v0 = *(const unsigned int*)(hlane + (size_t)s0 * 128);
            a0 += w * bf2f(v0 & 0xffff); a1 += w * bf2f(v0 >> 16);
        }
    }
    ssum = waveSum(ssum);
    float inv = 1.0f / (ssum + 1e-16f);
    a0 *= inv; a1 *= inv;

    unsigned int rv = *(const unsigned int*)(resb + (size_t)node * 128 + lane * 2);
    float o0 = a0 + bf2f(rv & 0xffff), o1 = a1 + bf2f(rv >> 16);
    const float SC = 1.0507009873554805f, AL = 1.6732632423543772f;
    o0 = (o0 > 0.f) ? SC * o0 : SC * AL * (__expf(o0) - 1.f);
    o1 = (o1 > 0.f) ? SC * o1 : SC * AL * (__expf(o1) - 1.f);
    *(float2*)(out + (size_t)node * 128 + lane * 2) = make_float2(o0, o1);
}

// ---------------- launch ----------------
extern "C" void kernel_launch(void* const* d_in, const int* in_sizes, int n_in,
                              void* d_out, int out_size, void* d_ws, size_t ws_size,
                              hipStream_t stream)
{
    const float* X      = (const float*)d_in[0];
    const int*   ei     = (const int*)d_in[1];
    const int*   etype  = (const int*)d_in[2];
    const float* W      = (const float*)d_in[3];
    const float* W_r    = (const float*)d_in[4];
    const float* a      = (const float*)d_in[5];
    const float* W_res  = (const float*)d_in[6];
    const float* b_res  = (const float*)d_in[7];
    const float* rel_emb= (const float*)d_in[8];

    const int N = in_sizes[0] / 128;     // 50000
    const int E = in_sizes[2];           // 600000
    const int n_rel = in_sizes[8] / 100; // 40
    const int* src = ei;
    const int* dst = ei + E;

    // workspace carve (256B aligned)
    char* w = (char*)d_ws;
    auto alloc = [&](size_t bytes) -> void* {
        void* ptr = (void*)w;
        w += (bytes + 255) & ~(size_t)255;
        return ptr;
    };
    unsigned short* WbPack = (unsigned short*)alloc((size_t)16 * 4 * 64 * 8 * 2);
    unsigned short* hb     = (unsigned short*)alloc((size_t)N * 128 * 2);
    unsigned short* resb   = (unsigned short*)alloc((size_t)N * 128 * 2);
    float* p       = (float*)alloc((size_t)N * 4);
    float* q       = (float*)alloc((size_t)N * 4);
    float* rl      = (float*)alloc(64 * 4);
    int*   counts  = (int*)alloc((size_t)N * 4);
    int*   tmp     = (int*)alloc((size_t)(N + 2) * 4);
    int*   offsets = (int*)alloc((size_t)(N + 2) * 4);
    int*   bsums   = (int*)alloc(256 * 4);
    int*   bpref   = (int*)alloc(256 * 4);
    int*   rank    = (int*)alloc((size_t)E * 4);
    uint2* pair0   = (uint2*)alloc((size_t)E * 8);
    uint2* pairs   = (uint2*)alloc((size_t)E * 8);
    float* out     = (float*)d_out;

    const int zb = (N + 255) / 256;                 // 196
    const int gemm_blocks = (N + 63) / 64;          // 782
    const int node_wave_blocks = (N + 3) / 4;       // 12500
    const int edge_blocks = (E + 255) / 256;        // 2344
    const int scan_blocks = (N + 1023) / 1024;      // 49

    setup_kernel<<<zb + 17, 256, 0, stream>>>(counts, N, W, W_res, WbPack,
                                              W_r, a, rel_emb, rl, n_rel, 100, zb);
    gemm_dual_kernel<<<gemm_blocks, 256, 0, stream>>>(X, WbPack, b_res, a, hb, resb, p, q, N);

    edge_kernel<<<edge_blocks, 256, 0, stream>>>(src, dst, etype, p, q, rl,
                                                 counts, rank, pair0, E, n_rel);
    scan_block<<<scan_blocks, 1024, 0, stream>>>(counts, tmp, bsums, N);
    scan_partials<<<1, 64, 0, stream>>>(bsums, bpref, scan_blocks);
    finalize_offsets<<<scan_blocks, 1024, 0, stream>>>(tmp, counts, bpref, offsets, N, E);

    scatter_kernel<<<edge_blocks, 256, 0, stream>>>(dst, rank, offsets, pair0, pairs, E);
    agg_kernel<<<node_wave_blocks, 256, 0, stream>>>(hb, resb, offsets, pairs, out, N);
}